// Round 6
// baseline (166.928 us; speedup 1.0000x reference)
//
#include <hip/hip_runtime.h>
#include <hip/hip_bf16.h>

typedef __attribute__((ext_vector_type(8))) short short8;       // 8 x bf16 (4 VGPR)
typedef __attribute__((ext_vector_type(4))) float f32x4;        // MFMA acc / float4
typedef __attribute__((ext_vector_type(2))) float f32x2;
typedef __attribute__((ext_vector_type(4))) unsigned short ushort4v;
typedef __attribute__((ext_vector_type(2))) unsigned int uint32x2;

__device__ __forceinline__ unsigned short f2bf(float f) {
    __hip_bfloat16 h = __float2bfloat16(f);
    return __builtin_bit_cast(unsigned short, h);
}
__device__ __forceinline__ unsigned int pack2(float a, float b) {
    return (unsigned int)f2bf(a) | ((unsigned int)f2bf(b) << 16);
}
__device__ __forceinline__ void gload_lds16(const void* g, void* l) {
    __builtin_amdgcn_global_load_lds((const __attribute__((address_space(1))) unsigned int*)g,
                                     (__attribute__((address_space(3))) unsigned int*)l, 16, 0, 0);
}

#define VMCNT(N) asm volatile("s_waitcnt vmcnt(" #N ")" ::: "memory")
#define LGKM0()  asm volatile("s_waitcnt lgkmcnt(0)" ::: "memory")

// ---------------- K0: W fp32 [256][512] -> wt bf16 tiled [u=k>>3][c][8] ----------------
// wt is exactly the LDS image k1 DMAs: tile kt (32 k = 4 u-slabs) = bytes [kt*16384, +16384).
__global__ __launch_bounds__(256) void k0_wt(const float* __restrict__ w,
                                             unsigned short* __restrict__ wt) {
    int T = blockIdx.x * 256 + threadIdx.x;     // 0..16383 slots
    int c = T & 255, u = T >> 8;                // writes coalesced (lanes -> c consecutive)
    const float* s = w + c * 512 + u * 8;
    f32x4 a = *(const f32x4*)s;
    f32x4 b = *(const f32x4*)(s + 4);
    short8 o;
    o[0] = (short)f2bf(a[0]); o[1] = (short)f2bf(a[1]);
    o[2] = (short)f2bf(a[2]); o[3] = (short)f2bf(a[3]);
    o[4] = (short)f2bf(b[0]); o[5] = (short)f2bf(b[1]);
    o[6] = (short)f2bf(b[2]); o[7] = (short)f2bf(b[3]);
    *(short8*)(wt + (size_t)(u * 256 + c) * 8) = o;
}

// ---------------- K1: Q-GEMM + normalize, counted-prefetch pipeline ----------------
// grid: 128 windows * 8 token-blocks (128 tok). block = 256 thr (4 waves).
// 1 barrier/iter; lA via linear DMA (dbuf), lB via reg-prefetched x (dbuf).
__global__ __launch_bounds__(256, 2) void k1_qgemm(const float* __restrict__ x,
                                                   const unsigned short* __restrict__ wt,
                                                   unsigned short* __restrict__ qn) {
    const int blk = blockIdx.x;
    const int win = blk >> 3;
    const int t0  = (blk & 7) << 7;
    const int b_  = win >> 2;
    const int h0  = ((win >> 1) & 1) << 5;
    const int w0  = (win & 1) << 5;

    __shared__ __align__(16) unsigned short lA[2][4 * 256 * 8];  // 2x16KB, slot [u_loc][c][8]
    __shared__ __align__(16) unsigned short lB[2][128][40];     // 2x10KB, [t][k] 80B rows
    __shared__ float nbuf[4][128];

    const int tid  = threadIdx.x;
    const int lane = tid & 63;
    const int wv   = tid >> 6;
    const int lo   = lane & 15;
    const int hi   = lane >> 4;

    f32x4 acc[4][8];
#pragma unroll
    for (int mi = 0; mi < 4; ++mi)
#pragma unroll
        for (int ni = 0; ni < 8; ++ni) acc[mi][ni] = (f32x4){0.f, 0.f, 0.f, 0.f};

    const float* xblk = x + (size_t)b_ * 512 * 4096 + (size_t)(h0 + (t0 >> 5)) * 64 + w0;
    const int tp  = tid & 63;
    const int cg  = tid >> 6;
    const int tt  = tp * 2;
    const int pos = ((tt >> 5) << 6) + (tt & 31);
    const float* xpbase = xblk + (size_t)(cg * 8) * 4096 + pos;

    f32x2 bregs[8];

#define K1_ISSUE_A(KT, BUF)                                                        \
    {                                                                              \
        const char* src_ = (const char*)wt + (size_t)(KT) * 16384;                 \
        char* dst_ = (char*)lA[BUF];                                               \
        _Pragma("unroll")                                                          \
        for (int r_ = 0; r_ < 4; ++r_) {                                           \
            int idx_ = (r_ * 256 + tid) * 16;                                      \
            gload_lds16(src_ + idx_, dst_ + idx_);                                 \
        }                                                                          \
    }
#define K1_LOAD_B(KT)                                                              \
    {                                                                              \
        const float* xp_ = xpbase + (size_t)(KT) * 32 * 4096;                      \
        _Pragma("unroll")                                                          \
        for (int i_ = 0; i_ < 8; ++i_) bregs[i_] = *(const f32x2*)(xp_ + (size_t)i_ * 4096); \
    }
#define K1_WRITE_B(BUF)                                                            \
    {                                                                              \
        short8 v0_, v1_;                                                           \
        _Pragma("unroll")                                                          \
        for (int i_ = 0; i_ < 8; ++i_) {                                           \
            v0_[i_] = (short)f2bf(bregs[i_][0]);                                   \
            v1_[i_] = (short)f2bf(bregs[i_][1]);                                   \
        }                                                                          \
        *(short8*)&lB[BUF][tt][cg * 8]     = v0_;                                  \
        *(short8*)&lB[BUF][tt + 1][cg * 8] = v1_;                                  \
    }

    // prologue: tile0 staged; tile1 x-loads in flight
    K1_ISSUE_A(0, 0);
    K1_LOAD_B(0);
    K1_WRITE_B(0);      // consumes bregs(0) (implicit vmcnt(0) also drains DMA0 - fine)
    K1_LOAD_B(1);

    for (int kt = 0; kt < 16; ++kt) {
        const int b = kt & 1;
        VMCNT(8);                            // DMA(kt) complete (Bload(kt+1) may pend)
        LGKM0();                             // my lB writes from last iter visible
        __builtin_amdgcn_s_barrier();        // lA[b]+lB[b] ready; compute(kt-1) done
        __builtin_amdgcn_sched_barrier(0);
        K1_WRITE_B(b ^ 1);                   // tile kt+1 (kt=15: dup, unused)
        {
            const int ktn = (kt + 1 < 16) ? kt + 1 : 15;
            K1_ISSUE_A(ktn, b ^ 1);
        }
        __builtin_amdgcn_sched_barrier(0);   // pin: DMA issued BEFORE B-loads (vmcnt order)
        {
            const int ktn2 = (kt + 2 < 16) ? kt + 2 : 15;
            K1_LOAD_B(ktn2);
        }
        __builtin_amdgcn_sched_barrier(0);

        short8 af[4], bfr[8];
#pragma unroll
        for (int mi = 0; mi < 4; ++mi)
            af[mi] = *(const short8*)&lA[b][(hi * 256 + wv * 64 + mi * 16 + lo) * 8];
#pragma unroll
        for (int ni = 0; ni < 8; ++ni)
            bfr[ni] = *(const short8*)&lB[b][ni * 16 + lo][hi * 8];
#pragma unroll
        for (int mi = 0; mi < 4; ++mi)
#pragma unroll
            for (int ni = 0; ni < 8; ++ni)
                acc[mi][ni] = __builtin_amdgcn_mfma_f32_16x16x32_bf16(af[mi], bfr[ni], acc[mi][ni], 0, 0, 0);
    }
    VMCNT(0);   // drain tail prefetches before epilogue/exit

    // ---- per-token norm over c ----
    float part[8];
#pragma unroll
    for (int ni = 0; ni < 8; ++ni) {
        float s = 0.f;
#pragma unroll
        for (int mi = 0; mi < 4; ++mi)
#pragma unroll
            for (int r = 0; r < 4; ++r) s += acc[mi][ni][r] * acc[mi][ni][r];
        s += __shfl_xor(s, 16);
        s += __shfl_xor(s, 32);
        part[ni] = s;
    }
    if (hi == 0) {
#pragma unroll
        for (int ni = 0; ni < 8; ++ni) nbuf[wv][ni * 16 + lo] = part[ni];
    }
    __syncthreads();

    char* qwin_out = (char*)(qn + (size_t)win * 1024 * 256);
#pragma unroll
    for (int ni = 0; ni < 8; ++ni) {
        const int tl = ni * 16 + lo;
        float s = nbuf[0][tl] + nbuf[1][tl] + nbuf[2][tl] + nbuf[3][tl];
        float inv = 1.f / (sqrtf(s) + 1e-6f);
        const int rq = t0 + tl;
        const int swz = (rq & 7) << 4;
#pragma unroll
        for (int mi = 0; mi < 4; ++mi) {
            int c = wv * 64 + mi * 16 + hi * 4;
            ushort4v o = {f2bf(acc[mi][ni][0] * inv), f2bf(acc[mi][ni][1] * inv),
                          f2bf(acc[mi][ni][2] * inv), f2bf(acc[mi][ni][3] * inv)};
            size_t off = ((size_t)rq * 512 + (size_t)(c * 2)) ^ (size_t)swz;
            *(ushort4v*)(qwin_out + off) = o;
        }
    }
}

// ---------------- K2: S^T + PV, counted-prefetch, 32-key dbuf chunks ----------------
// grid: 512 = 128 windows * 4 query-blocks (256 q); bid&127 = window (XCD swizzle).
__global__ __launch_bounds__(256, 2) void k2_attn(const unsigned short* __restrict__ qn,
                                                  const float* __restrict__ v,
                                                  float* __restrict__ out) {
    const int g   = blockIdx.x;
    const int win = g & 127;
    const int qb  = g >> 7;
    const int b_  = win >> 2;
    const int h0  = ((win >> 1) & 1) << 5;
    const int w0  = (win & 1) << 5;

    __shared__ __align__(16) unsigned short lK[2][32 * 256];  // 2x16KB swizzled key image
    __shared__ __align__(16) unsigned short lP[256][36];      // 72B rows, wave-private
    __shared__ __align__(16) unsigned short lV[2][16][36];    // V^T [ch][key], row15 = ones

    const int tid  = threadIdx.x;
    const int lane = tid & 63;
    const int wv   = tid >> 6;
    const int lo   = lane & 15;
    const int hi   = lane >> 4;

    const char* qwin = (const char*)(qn + (size_t)win * 1024 * 256);
    const int qw0 = qb * 256 + wv * 64;

    // hoisted Q fragments (swizzled reads)
    short8 qa[4][8];
#pragma unroll
    for (int mi = 0; mi < 4; ++mi) {
        const int rq = qw0 + mi * 16 + lo;
        const size_t swz = (size_t)((rq & 7) << 4);
#pragma unroll
        for (int kc = 0; kc < 8; ++kc)
            qa[mi][kc] = *(const short8*)(qwin + (((size_t)rq * 512 + kc * 64 + hi * 16) ^ swz));
    }

    f32x4 accout[4];
#pragma unroll
    for (int t = 0; t < 4; ++t) accout[t] = (f32x4){0.f, 0.f, 0.f, 0.f};

    const float* vbase = v + (size_t)b_ * 15 * 4096 + (size_t)h0 * 64 + w0;
    const int chn = tid & 15;
    const int kp  = tid >> 4;
    const float* vch = vbase + (size_t)(chn < 15 ? chn : 14) * 4096;  // clamped, uniform issue
    f32x2 vpre;

    // ---- prologue ----
    {
        f32x2 d = *(const f32x2*)(vch + kp * 2);
        unsigned int u0 = (chn < 15) ? pack2(d[0], d[1]) : 0x3F803F80u;
        *(unsigned int*)((char*)lV[0] + chn * 72 + kp * 4) = u0;
    }
    {
        char* dst = (char*)lK[0];
#pragma unroll
        for (int r = 0; r < 4; ++r) { int idx = (r * 256 + tid) * 16; gload_lds16(qwin + idx, dst + idx); }
    }
    vpre = *(const f32x2*)(vch + 64 + kp * 2);   // chunk 1

    for (int chk = 0; chk < 32; ++chk) {
        const int b = chk & 1;
        VMCNT(1);                            // DMA(chk) complete (vpre may pend)
        LGKM0();                             // prior lV/lP writes drained
        __builtin_amdgcn_s_barrier();
        __builtin_amdgcn_sched_barrier(0);
        // write lV[b^1] <- vpre (chunk chk+1); readers only after next barrier
        {
            unsigned int u = (chn < 15) ? pack2(vpre[0], vpre[1]) : 0x3F803F80u;
            *(unsigned int*)((char*)lV[b ^ 1] + chn * 72 + kp * 4) = u;
        }
        // issue DMA(chk+1 -> lK[b^1]) (post-barrier: nobody reads lK[b^1] anymore)
        {
            const int cn = (chk + 1 < 32) ? chk + 1 : 31;
            const char* src = qwin + (size_t)cn * 16384;
            char* dst = (char*)lK[b ^ 1];
#pragma unroll
            for (int r = 0; r < 4; ++r) { int idx = (r * 256 + tid) * 16; gload_lds16(src + idx, dst + idx); }
        }
        __builtin_amdgcn_sched_barrier(0);   // pin: DMA issued BEFORE vpre load (vmcnt order)
        // issue Vload(chk+2)
        {
            const int cv = (chk + 2 < 32) ? chk + 2 : 31;
            vpre = *(const f32x2*)(vch + cv * 64 + kp * 2);
        }
        __builtin_amdgcn_sched_barrier(0);

        // ---- S^T on lK[b]: D = mfma(A=kb, B=qa) ----
        const char* lKb = (const char*)lK[b];
#pragma unroll
        for (int ni = 0; ni < 2; ++ni) {
            f32x4 st[4];
#pragma unroll
            for (int mi = 0; mi < 4; ++mi) st[mi] = (f32x4){0.f, 0.f, 0.f, 0.f};
#pragma unroll
            for (int kc = 0; kc < 8; ++kc) {
                const int row = ni * 16 + lo;
                const int off = (row * 512 + kc * 64 + hi * 16) ^ ((row & 7) << 4);
                short8 kb = *(const short8*)(lKb + off);
#pragma unroll
                for (int mi = 0; mi < 4; ++mi)
                    st[mi] = __builtin_amdgcn_mfma_f32_16x16x32_bf16(kb, qa[mi][kc], st[mi], 0, 0, 0);
            }
#pragma unroll
            for (int mi = 0; mi < 4; ++mi) {
                uint32x2 u;
                u[0] = pack2(fmaxf(st[mi][0], 0.f), fmaxf(st[mi][1], 0.f));
                u[1] = pack2(fmaxf(st[mi][2], 0.f), fmaxf(st[mi][3], 0.f));
                *(uint32x2*)((char*)&lP[0][0] + (wv * 64 + mi * 16 + lo) * 72 + ni * 32 + hi * 8) = u;
            }
        }
        // ---- PV on lP + lV[b] (wave-private lP rows; K=32 -> 1 MFMA per t) ----
        {
            short8 vbf = *(const short8*)((const char*)lV[b] + lo * 72 + hi * 16);
#pragma unroll
            for (int t = 0; t < 4; ++t) {
                short8 pa = *(const short8*)((const char*)&lP[0][0] + (wv * 64 + t * 16 + lo) * 72 + hi * 16);
                accout[t] = __builtin_amdgcn_mfma_f32_16x16x32_bf16(pa, vbf, accout[t], 0, 0, 0);
            }
        }
    }
    VMCNT(0);   // drain tail prefetches before exit

    // epilogue: divide by rowsum (ch 15) and store. D: lane lo = channel, (hi,r) = q.
#pragma unroll
    for (int t = 0; t < 4; ++t) {
#pragma unroll
        for (int r = 0; r < 4; ++r) {
            float rs = __shfl(accout[t][r], (lane & 48) | 15);
            if (lo < 15) {
                int q = qw0 + t * 16 + hi * 4 + r;
                out[(size_t)(b_ * 15 + lo) * 4096 + (size_t)(h0 + (q >> 5)) * 64 + (w0 + (q & 31))] =
                    accout[t][r] / (rs + 1e-6f);
            }
        }
    }
}

extern "C" void kernel_launch(void* const* d_in, const int* in_sizes, int n_in,
                              void* d_out, int out_size, void* d_ws, size_t ws_size,
                              hipStream_t stream) {
    const float* x = (const float*)d_in[0];
    const float* v = (const float*)d_in[1];
    const float* w = (const float*)d_in[2];
    float* out = (float*)d_out;

    unsigned short* qn = (unsigned short*)d_ws;                          // 64 MiB (swizzled)
    unsigned short* wt = (unsigned short*)((char*)d_ws + (size_t)128 * 1024 * 256 * 2);  // 256 KiB tiled W

    k0_wt<<<64, 256, 0, stream>>>(w, wt);
    k1_qgemm<<<1024, 256, 0, stream>>>(x, wt, qn);
    k2_attn<<<512, 256, 0, stream>>>(qn, v, out);
}